// Round 2
// baseline (481.716 us; speedup 1.0000x reference)
//
#include <hip/hip_runtime.h>

// Temporally-blocked Jacobi, register-resident + packed-fp32: 5 x 10 steps.
// v3 — tall patches. Each thread owns an 8x4 patch (tile 128x64, OUT 108x44):
//  * halo-redundancy drops 2.11x -> 1.73x (total computed cells 0.83x)
//  * LDS exchange fraction drops 50% -> 25% of cells (same 4 b128 wave-ops
//    per step per wave, but covering 2x the cells) -> LDS pipe time ~0.4x
//  * same slot scheme as v2: 32 boundary rows + 2 dummies, double-buffered,
//    one __syncthreads per step; step-0 exchange populates interior halos,
//    only tile rows 0/129 staged explicitly (stale after step 0 -> rows
//    outside the kept 10..117 window, same tolerance as v2).
// VGPR ~2x (E,O,fE,fO = 64 regs state) -> ~5 waves/SIMD; v2 proved this
// kernel is not occupancy-limited (39%->77% gave only 6%).

#define NX 1024
#define BATCH 16
#define TSTEPS 10
#define OUTC 44
#define OUTR 108
#define HIC 53           // last valid data col
#define HIR 117          // last valid data row
#define PITCH 64
#define SLOTS 34         // slot 0 and 33 are write-dummies for chunks 0/15

typedef float v2f __attribute__((ext_vector_type(2)));

__device__ __forceinline__ int reflect_idx(int i) {
    i = (i < 0) ? -i : i;
    return (i > NX - 1) ? 2 * (NX - 1) - i : i;
}

// lane g gets lane g-1's value within each 16-lane DPP row (edges keep own: garbage-allowed)
__device__ __forceinline__ float dpp_shr1(float x) {
    int v = __float_as_int(x);
    return __int_as_float(__builtin_amdgcn_update_dpp(v, v, 0x111, 0xF, 0xF, false));
}
__device__ __forceinline__ float dpp_shl1(float x) {
    int v = __float_as_int(x);
    return __int_as_float(__builtin_amdgcn_update_dpp(v, v, 0x101, 0xF, 0xF, false));
}

__device__ __forceinline__ v2f pk_add(v2f a, v2f b) {
    v2f d; asm("v_pk_add_f32 %0, %1, %2" : "=v"(d) : "v"(a), "v"(b)); return d;
}
__device__ __forceinline__ v2f pk_fma(v2f a, v2f b, v2f c) {
    v2f d; asm("v_pk_fma_f32 %0, %1, %2, %3" : "=v"(d) : "v"(a), "v"(b), "v"(c)); return d;
}

__global__ __launch_bounds__(256, 5) void jacobi_fused(const float* __restrict__ src,
                                                       const float* __restrict__ layout,
                                                       float* __restrict__ dst) {
    __shared__ float buf[2][SLOTS * PITCH];

    const float COF = (float)(0.25 * (0.1 / 1023.0) * (0.1 / 1023.0));

    const int tid = threadIdx.x;
    const int g = tid & 15;                      // col group: data cols 4g..4g+3
    const int c = tid >> 4;                      // row chunk: rows 1+8c..8+8c
    const int gr0 = blockIdx.y * OUTR - TSTEPS;
    const int gc0 = blockIdx.x * OUTC - TSTEPS;
    const int base = blockIdx.z * NX * NX;
    const int R0 = 1 + 8 * c;
    const int C0 = 4 * g;

    v2f E[8], O[8], fE[8], fO[8];

    const bool interior = (blockIdx.x >= 1) && (blockIdx.x <= 22) &&
                          (blockIdx.y >= 1) && (blockIdx.y <= 8);

    if (interior) {
        // ---- fast staging: 8x4 patch + f straight to registers ----
        const float* sb = src + base + (gr0 + R0) * NX + gc0 + C0;
        const float* lb = layout + base + (gr0 + R0) * NX + gc0 + C0;
#pragma unroll
        for (int i = 0; i < 8; ++i) {
            v2f a = *(const v2f*)(sb + i * NX);        // cols C0, C0+1 (8B-aligned)
            v2f b = *(const v2f*)(sb + i * NX + 2);    // cols C0+2, C0+3
            E[i] = (v2f){a.x, b.x};
            O[i] = (v2f){a.y, b.y};
        }
#pragma unroll
        for (int i = 0; i < 8; ++i) {
            v2f a = *(const v2f*)(lb + i * NX);
            v2f b = *(const v2f*)(lb + i * NX + 2);
            fE[i] = (v2f){COF * a.x, COF * b.x};
            fO[i] = (v2f){COF * a.y, COF * b.y};
        }
        // global halo rows 0 and 129 -> slots 1 and 32 (bit-swapped E/O layout)
        if (tid < 64) {
            const int rsel = tid >> 5;                 // 0: row 0, 1: row 129
            const int q2 = tid & 31;                   // col pair 2q2, 2q2+1
            const int slot = rsel ? 32 : 1;
            v2f v = *(const v2f*)(src + base + (gr0 + (rsel ? 129 : 0)) * NX + gc0 + 2 * q2);
            const int lo = 4 * (q2 >> 1) + (q2 & 1);
            buf[0][slot * PITCH + lo]     = v.x;
            buf[0][slot * PITCH + lo + 2] = v.y;
        }
    } else {
        // ---- slow staging: reflect-mapped scalar loads ----
        const int c0 = reflect_idx(gc0 + C0);
        const int c1 = reflect_idx(gc0 + C0 + 1);
        const int c2 = reflect_idx(gc0 + C0 + 2);
        const int c3 = reflect_idx(gc0 + C0 + 3);
#pragma unroll
        for (int i = 0; i < 8; ++i) {
            const int grr = reflect_idx(gr0 + R0 + i);
            const float* sr = src + base + grr * NX;
            const float* lr = layout + base + grr * NX;
            E[i]  = (v2f){sr[c0], sr[c2]};
            O[i]  = (v2f){sr[c1], sr[c3]};
            fE[i] = (v2f){COF * lr[c0], COF * lr[c2]};
            fO[i] = (v2f){COF * lr[c1], COF * lr[c3]};
        }
        if (tid < 128) {
            const int rsel = tid >> 6;
            const int q = tid & 63;
            const int slot = rsel ? 32 : 1;
            const int grr = reflect_idx(gr0 + (rsel ? 129 : 0));
            const int lo = (q & ~3) | ((q & 1) << 1) | ((q >> 1) & 1);   // swap low 2 bits
            buf[0][slot * PITCH + lo] = src[base + grr * NX + reflect_idx(gc0 + q)];
        }
    }

    const v2f qq = (v2f){0.25f, 0.25f};
    const int wT = (2 * c) * PITCH + C0;         // row R0   = bottom halo of chunk c-1
    const int wB = (2 * c + 3) * PITCH + C0;     // row R0+7 = top halo of chunk c+1
    const int rT = (2 * c + 1) * PITCH + C0;     // own top halo (row 8c)
    const int rB = (2 * c + 2) * PITCH + C0;     // own bottom halo (row 8c+9)

    // ---- 10 fused steps; one barrier per step ----
#pragma unroll
    for (int s = 0; s < TSTEPS; ++s) {
        float* bb = buf[s & 1];
        *(float4*)&bb[wT] = make_float4(E[0].x, E[0].y, O[0].x, O[0].y);
        *(float4*)&bb[wB] = make_float4(E[7].x, E[7].y, O[7].x, O[7].y);
        __syncthreads();
        const float4 t  = *(const float4*)&bb[rT];
        const float4 bo = *(const float4*)&bb[rB];
        v2f upE = (v2f){t.x, t.y};
        v2f upO = (v2f){t.z, t.w};
        const v2f botE = (v2f){bo.x, bo.y};
        const v2f botO = (v2f){bo.z, bo.w};
#pragma unroll
        for (int i = 0; i < 8; ++i) {
            v2f dnE = (i == 7) ? botE : E[i + 1];
            v2f dnO = (i == 7) ? botO : O[i + 1];
            v2f vE = pk_add(upE, dnE);
            v2f vO = pk_add(upO, dnO);
            v2f P; P.x = dpp_shr1(O[i].y); P.y = O[i].x;   // (lf, c1)
            v2f Q; Q.x = E[i].y; Q.y = dpp_shl1(E[i].x);   // (c2, rt)
            v2f hE = pk_add(P, O[i]);                      // (lf+c1, c1+c3)
            v2f hO = pk_add(E[i], Q);                      // (c0+c2, c2+rt)
            upE = E[i]; upO = O[i];                        // old center = next row's up
            E[i] = pk_fma(pk_add(vE, hE), qq, fE[i]);
            O[i] = pk_fma(pk_add(vO, hO), qq, fO[i]);
        }
    }

    // ---- store central 108x44 window from registers (paired 8B stores) ----
    const int dc0 = C0;          // pair0: cols C0, C0+1
    const int dc2 = C0 + 2;      // pair1: cols C0+2, C0+3
    const bool ok0c = (dc0 >= TSTEPS) && (dc0 <= HIC - 1) && (gc0 + dc0 + 1 < NX);
    const bool ok1c = (dc2 >= TSTEPS) && (dc2 <= HIC - 1) && (gc0 + dc2 + 1 < NX);
#pragma unroll
    for (int i = 0; i < 8; ++i) {
        const int br = R0 + i;
        const bool rowok = (br >= TSTEPS) && (br <= HIR) && (gr0 + br < NX);
        if (rowok && ok0c)
            *(v2f*)(dst + base + (gr0 + br) * NX + gc0 + dc0) = (v2f){E[i].x, O[i].x};
        if (rowok && ok1c)
            *(v2f*)(dst + base + (gr0 + br) * NX + gc0 + dc2) = (v2f){E[i].y, O[i].y};
    }
}

extern "C" void kernel_launch(void* const* d_in, const int* in_sizes, int n_in,
                              void* d_out, int out_size, void* d_ws, size_t ws_size,
                              hipStream_t stream) {
    const float* layout = (const float*)d_in[0];
    const float* heat   = (const float*)d_in[1];
    float* out = (float*)d_out;
    float* ws  = (float*)d_ws;

    dim3 grid((NX + OUTC - 1) / OUTC, (NX + OUTR - 1) / OUTR, BATCH);  // 24 x 10 x 16
    dim3 block(256);

    jacobi_fused<<<grid, block, 0, stream>>>(heat, layout, out);
    jacobi_fused<<<grid, block, 0, stream>>>(out,  layout, ws);
    jacobi_fused<<<grid, block, 0, stream>>>(ws,   layout, out);
    jacobi_fused<<<grid, block, 0, stream>>>(out,  layout, ws);
    jacobi_fused<<<grid, block, 0, stream>>>(ws,   layout, out);
}

// Round 3
// 379.799 us; speedup vs baseline: 1.2683x; 1.2683x over previous
//
#include <hip/hip_runtime.h>

// Temporally-blocked Jacobi, register-resident + packed-fp32.
// v4 — 512-thread blocks, 128x128 tiles, 4 dispatches (T=13,13,13,11):
//  * kept window = 96 cols starting at tile col 16 -> global store base 96*bx
//    is 64B-aligned, 96 cols = 6 full lines: no partial-line writes, no
//    write-allocate fetch (v3: WRITE_SIZE 104MB vs 67MB output)
//  * one wave spans the full 128-col width (32 col-groups x 2 row-chunks);
//    horizontal neighbors via wave_shr1/wave_shl1 DPP (0x138/0x130) so the
//    only shift seams are tile edges where garbage is already tolerated
//  * 4 dispatches x {13,13,13,11} steps = 50; grid 11x10x16 = 1760 blocks for
//    both T -> same total cell-updates as 5x10, minus one full write+read
//    round (~130MB) and one launch
//  * same LDS slot scheme (34 boundary-row slots, double-buffered, PITCH 128,
//    one barrier/step); halo rows 0/129 staged to buf[0] only; wrong-front
//    advances 1 row/col per step so rows/cols T..(129-T / 127-T) are exact.
//  * staging is one aligned float4 per row (gc0 = 96bx-16 -> 16B aligned)

#define NX 1024
#define BATCH 16
#define OUTC 96
#define T16 16           // first kept tile-local col (multiple of 16)
#define PITCH 128
#define SLOTS 34         // slot 0 and 33 are write-dummies for chunks 0/15

typedef float v2f __attribute__((ext_vector_type(2)));

__device__ __forceinline__ int reflect_idx(int i) {
    i = (i < 0) ? -i : i;
    return (i > NX - 1) ? 2 * (NX - 1) - i : i;
}

// whole-wave lane shifts; edge lanes keep own value (garbage-allowed: they
// correspond to tile cols 0/127 or chunk seams, all outside the kept window)
__device__ __forceinline__ float dpp_wshr1(float x) {   // lane l <- lane l-1
    int v = __float_as_int(x);
    return __int_as_float(__builtin_amdgcn_update_dpp(v, v, 0x138, 0xF, 0xF, false));
}
__device__ __forceinline__ float dpp_wshl1(float x) {   // lane l <- lane l+1
    int v = __float_as_int(x);
    return __int_as_float(__builtin_amdgcn_update_dpp(v, v, 0x130, 0xF, 0xF, false));
}

__device__ __forceinline__ v2f pk_add(v2f a, v2f b) {
    v2f d; asm("v_pk_add_f32 %0, %1, %2" : "=v"(d) : "v"(a), "v"(b)); return d;
}
__device__ __forceinline__ v2f pk_fma(v2f a, v2f b, v2f c) {
    v2f d; asm("v_pk_fma_f32 %0, %1, %2, %3" : "=v"(d) : "v"(a), "v"(b), "v"(c)); return d;
}

template<int T, int OUTR>
__global__ __launch_bounds__(512, 4) void jacobi_fused(const float* __restrict__ src,
                                                       const float* __restrict__ layout,
                                                       float* __restrict__ dst) {
    __shared__ float buf[2][SLOTS * PITCH];

    const float COF = (float)(0.25 * (0.1 / 1023.0) * (0.1 / 1023.0));

    const int tid = threadIdx.x;
    const int g = tid & 31;                      // col group: tile cols 4g..4g+3
    const int c = tid >> 5;                      // row chunk: tile rows 1+8c..8+8c
    const int gr0 = blockIdx.y * OUTR - T;
    const int gc0 = blockIdx.x * OUTC - T16;
    const int base = blockIdx.z * NX * NX;
    const int R0 = 1 + 8 * c;
    const int C0 = 4 * g;

    v2f E[8], O[8], fE[8], fO[8];

    // fetched region: rows gr0..gr0+129, cols gc0..gc0+127 in-bounds?
    const bool interior = (blockIdx.x >= 1) && (blockIdx.x <= 9) &&
                          (blockIdx.y >= 1) && (blockIdx.y <= 8);

    if (interior) {
        // ---- fast staging: 8x4 patch + f via aligned float4 loads ----
        const float* sb = src + base + (gr0 + R0) * NX + gc0 + C0;
        const float* lb = layout + base + (gr0 + R0) * NX + gc0 + C0;
#pragma unroll
        for (int i = 0; i < 8; ++i) {
            float4 v = *(const float4*)(sb + i * NX);
            E[i] = (v2f){v.x, v.z};
            O[i] = (v2f){v.y, v.w};
        }
#pragma unroll
        for (int i = 0; i < 8; ++i) {
            float4 v = *(const float4*)(lb + i * NX);
            fE[i] = (v2f){COF * v.x, COF * v.z};
            fO[i] = (v2f){COF * v.y, COF * v.w};
        }
        // global halo rows 0 and 129 -> slots 1 and 32 (bit-swapped E/O layout)
        if (tid < 128) {
            const int rsel = tid >> 6;                 // 0: row 0, 1: row 129
            const int q2 = tid & 63;                   // col pair 2q2, 2q2+1
            const int slot = rsel ? 32 : 1;
            v2f v = *(const v2f*)(src + base + (gr0 + (rsel ? 129 : 0)) * NX + gc0 + 2 * q2);
            const int lo = 4 * (q2 >> 1) + (q2 & 1);
            buf[0][slot * PITCH + lo]     = v.x;
            buf[0][slot * PITCH + lo + 2] = v.y;
        }
    } else {
        // ---- slow staging: reflect-mapped scalar loads ----
        const int c0 = reflect_idx(gc0 + C0);
        const int c1 = reflect_idx(gc0 + C0 + 1);
        const int c2 = reflect_idx(gc0 + C0 + 2);
        const int c3 = reflect_idx(gc0 + C0 + 3);
#pragma unroll
        for (int i = 0; i < 8; ++i) {
            const int grr = reflect_idx(gr0 + R0 + i);
            const float* sr = src + base + grr * NX;
            const float* lr = layout + base + grr * NX;
            E[i]  = (v2f){sr[c0], sr[c2]};
            O[i]  = (v2f){sr[c1], sr[c3]};
            fE[i] = (v2f){COF * lr[c0], COF * lr[c2]};
            fO[i] = (v2f){COF * lr[c1], COF * lr[c3]};
        }
        if (tid < 256) {
            const int rsel = tid >> 7;                 // 0: row 0, 1: row 129
            const int q = tid & 127;
            const int slot = rsel ? 32 : 1;
            const int grr = reflect_idx(gr0 + (rsel ? 129 : 0));
            const int lo = (q & ~3) | ((q & 1) << 1) | ((q >> 1) & 1);   // swap low 2 bits
            buf[0][slot * PITCH + lo] = src[base + grr * NX + reflect_idx(gc0 + q)];
        }
    }

    const v2f qq = (v2f){0.25f, 0.25f};
    const int wT = (2 * c) * PITCH + C0;         // row R0   = bottom halo of chunk c-1
    const int wB = (2 * c + 3) * PITCH + C0;     // row R0+7 = top halo of chunk c+1
    const int rT = (2 * c + 1) * PITCH + C0;     // own top halo (row 8c)
    const int rB = (2 * c + 2) * PITCH + C0;     // own bottom halo (row 8c+9)

    // ---- T fused steps; one barrier per step ----
#pragma unroll
    for (int s = 0; s < T; ++s) {
        float* bb = buf[s & 1];
        *(float4*)&bb[wT] = make_float4(E[0].x, E[0].y, O[0].x, O[0].y);
        *(float4*)&bb[wB] = make_float4(E[7].x, E[7].y, O[7].x, O[7].y);
        __syncthreads();
        const float4 t  = *(const float4*)&bb[rT];
        const float4 bo = *(const float4*)&bb[rB];
        v2f upE = (v2f){t.x, t.y};
        v2f upO = (v2f){t.z, t.w};
        const v2f botE = (v2f){bo.x, bo.y};
        const v2f botO = (v2f){bo.z, bo.w};
#pragma unroll
        for (int i = 0; i < 8; ++i) {
            v2f dnE = (i == 7) ? botE : E[i + 1];
            v2f dnO = (i == 7) ? botO : O[i + 1];
            v2f vE = pk_add(upE, dnE);
            v2f vO = pk_add(upO, dnO);
            v2f P; P.x = dpp_wshr1(O[i].y); P.y = O[i].x;   // (lf, c1)
            v2f Q; Q.x = E[i].y; Q.y = dpp_wshl1(E[i].x);   // (c2, rt)
            v2f hE = pk_add(P, O[i]);                       // (lf+c1, c1+c3)
            v2f hO = pk_add(E[i], Q);                       // (c0+c2, c2+rt)
            upE = E[i]; upO = O[i];                         // old center = next row's up
            E[i] = pk_fma(pk_add(vE, hE), qq, fE[i]);
            O[i] = pk_fma(pk_add(vO, hO), qq, fO[i]);
        }
    }

    // ---- store kept window: rows T..129-T, tile cols 16..111 (aligned) ----
    const bool ok0 = (C0 >= T16) && (C0 < T16 + OUTC) && (gc0 + C0 + 1 < NX);
    const bool ok1 = (C0 + 2 >= T16) && (C0 + 2 < T16 + OUTC) && (gc0 + C0 + 3 < NX);
#pragma unroll
    for (int i = 0; i < 8; ++i) {
        const int br = R0 + i;
        const bool rowok = (br >= T) && (br <= 129 - T) && (gr0 + br < NX);
        if (rowok && ok0)
            *(v2f*)(dst + base + (gr0 + br) * NX + gc0 + C0) = (v2f){E[i].x, O[i].x};
        if (rowok && ok1)
            *(v2f*)(dst + base + (gr0 + br) * NX + gc0 + C0 + 2) = (v2f){E[i].y, O[i].y};
    }
}

extern "C" void kernel_launch(void* const* d_in, const int* in_sizes, int n_in,
                              void* d_out, int out_size, void* d_ws, size_t ws_size,
                              hipStream_t stream) {
    const float* layout = (const float*)d_in[0];
    const float* heat   = (const float*)d_in[1];
    float* out = (float*)d_out;
    float* ws  = (float*)d_ws;

    // T=13: OUTR = 130-2*13 = 104 -> grid rows ceil(1024/104) = 10
    // T=11: OUTR = 130-2*11 = 108 -> grid rows ceil(1024/108) = 10
    const dim3 g13(11, 10, BATCH), g11(11, 10, BATCH);
    const dim3 block(512);

    jacobi_fused<13, 104><<<g13, block, 0, stream>>>(heat, layout, ws);
    jacobi_fused<13, 104><<<g13, block, 0, stream>>>(ws,   layout, out);
    jacobi_fused<13, 104><<<g13, block, 0, stream>>>(out,  layout, ws);
    jacobi_fused<11, 108><<<g11, block, 0, stream>>>(ws,   layout, out);
}

// Round 5
// 374.394 us; speedup vs baseline: 1.2867x; 1.0144x over previous
//
#include <hip/hip_runtime.h>

// Temporally-blocked Jacobi, register-resident + packed-fp32.
// v5 — convoy/latency restructure of v4 (same 128x128 tiles, 512 threads,
// 4 dispatches T=13,13,13,11, same compulsory-traffic staging/stores):
//  * per step: barrier -> issue halo ds_reads -> compute rows 1..3 (reg-only,
//    hides lgkm) -> row 0 (uses top halo) -> write new row0 (other buffer)
//    -> rows 4..6 -> row 7 (uses bottom halo) -> write new row7.
//    Boundary writes land mid-step so barrier arrivals de-phase; reads get
//    ~40 independent VALU instrs of cover before first use.
//  * staging writes the S0 boundary rows itself (iter 0 reads full buf[0]);
//    last iteration's writes elided.
//  * exchange writes are 2x ds_write_b64 straight from E/O reg pairs (no
//    float4 assembly movs).
// Cell arithmetic is op-identical to v4 -> bit-identical output.
// (Round 4 rerun: previous bench failed on container acquisition, not kernel.)

#define NX 1024
#define BATCH 16
#define OUTC 96
#define T16 16           // first kept tile-local col (multiple of 16)
#define PITCH 128
#define SLOTS 34         // slot 0 and 33 are write-dummies for chunks 0/15

typedef float v2f __attribute__((ext_vector_type(2)));

__device__ __forceinline__ int reflect_idx(int i) {
    i = (i < 0) ? -i : i;
    return (i > NX - 1) ? 2 * (NX - 1) - i : i;
}

// whole-wave lane shifts; edge lanes keep own value (garbage-allowed: they
// correspond to tile cols 0/127, outside the kept window)
__device__ __forceinline__ float dpp_wshr1(float x) {   // lane l <- lane l-1
    int v = __float_as_int(x);
    return __int_as_float(__builtin_amdgcn_update_dpp(v, v, 0x138, 0xF, 0xF, false));
}
__device__ __forceinline__ float dpp_wshl1(float x) {   // lane l <- lane l+1
    int v = __float_as_int(x);
    return __int_as_float(__builtin_amdgcn_update_dpp(v, v, 0x130, 0xF, 0xF, false));
}

__device__ __forceinline__ v2f pk_add(v2f a, v2f b) {
    v2f d; asm("v_pk_add_f32 %0, %1, %2" : "=v"(d) : "v"(a), "v"(b)); return d;
}
__device__ __forceinline__ v2f pk_fma(v2f a, v2f b, v2f c) {
    v2f d; asm("v_pk_fma_f32 %0, %1, %2, %3" : "=v"(d) : "v"(a), "v"(b), "v"(c)); return d;
}

// one stencil row: up/center/down E,O pairs + f -> result E,O
__device__ __forceinline__ void jrow(v2f uE, v2f uO, v2f cE, v2f cO,
                                     v2f dE, v2f dO, v2f fe, v2f fo,
                                     v2f qq, v2f& rE, v2f& rO) {
    v2f vE = pk_add(uE, dE);
    v2f vO = pk_add(uO, dO);
    v2f P; P.x = dpp_wshr1(cO.y); P.y = cO.x;   // (lf, c1)
    v2f Q; Q.x = cE.y; Q.y = dpp_wshl1(cE.x);   // (c2, rt)
    v2f hE = pk_add(P, cO);                     // (lf+c1, c1+c3)
    v2f hO = pk_add(cE, Q);                     // (c0+c2, c2+rt)
    rE = pk_fma(pk_add(vE, hE), qq, fe);
    rO = pk_fma(pk_add(vO, hO), qq, fo);
}

template<int T, int OUTR>
__global__ __launch_bounds__(512, 4) void jacobi_fused(const float* __restrict__ src,
                                                       const float* __restrict__ layout,
                                                       float* __restrict__ dst) {
    __shared__ float buf[2][SLOTS * PITCH];

    const float COF = (float)(0.25 * (0.1 / 1023.0) * (0.1 / 1023.0));

    const int tid = threadIdx.x;
    const int g = tid & 31;                      // col group: tile cols 4g..4g+3
    const int c = tid >> 5;                      // row chunk: tile rows 1+8c..8+8c
    const int gr0 = blockIdx.y * OUTR - T;
    const int gc0 = blockIdx.x * OUTC - T16;
    const int base = blockIdx.z * NX * NX;
    const int R0 = 1 + 8 * c;
    const int C0 = 4 * g;

    v2f E[8], O[8], fE[8], fO[8];

    const bool interior = (blockIdx.x >= 1) && (blockIdx.x <= 9) &&
                          (blockIdx.y >= 1) && (blockIdx.y <= 8);

    if (interior) {
        // ---- fast staging: 8x4 patch + f via aligned float4 loads ----
        const float* sb = src + base + (gr0 + R0) * NX + gc0 + C0;
        const float* lb = layout + base + (gr0 + R0) * NX + gc0 + C0;
#pragma unroll
        for (int i = 0; i < 8; ++i) {
            float4 v = *(const float4*)(sb + i * NX);
            E[i] = (v2f){v.x, v.z};
            O[i] = (v2f){v.y, v.w};
        }
#pragma unroll
        for (int i = 0; i < 8; ++i) {
            float4 v = *(const float4*)(lb + i * NX);
            fE[i] = (v2f){COF * v.x, COF * v.z};
            fO[i] = (v2f){COF * v.y, COF * v.w};
        }
        // global halo rows 0 and 129 -> slots 1 and 32 (bit-swapped E/O layout)
        if (tid < 128) {
            const int rsel = tid >> 6;                 // 0: row 0, 1: row 129
            const int q2 = tid & 63;                   // col pair 2q2, 2q2+1
            const int slot = rsel ? 32 : 1;
            v2f v = *(const v2f*)(src + base + (gr0 + (rsel ? 129 : 0)) * NX + gc0 + 2 * q2);
            const int lo = 4 * (q2 >> 1) + (q2 & 1);
            buf[0][slot * PITCH + lo]     = v.x;
            buf[0][slot * PITCH + lo + 2] = v.y;
        }
    } else {
        // ---- slow staging: reflect-mapped scalar loads ----
        const int c0 = reflect_idx(gc0 + C0);
        const int c1 = reflect_idx(gc0 + C0 + 1);
        const int c2 = reflect_idx(gc0 + C0 + 2);
        const int c3 = reflect_idx(gc0 + C0 + 3);
#pragma unroll
        for (int i = 0; i < 8; ++i) {
            const int grr = reflect_idx(gr0 + R0 + i);
            const float* sr = src + base + grr * NX;
            const float* lr = layout + base + grr * NX;
            E[i]  = (v2f){sr[c0], sr[c2]};
            O[i]  = (v2f){sr[c1], sr[c3]};
            fE[i] = (v2f){COF * lr[c0], COF * lr[c2]};
            fO[i] = (v2f){COF * lr[c1], COF * lr[c3]};
        }
        if (tid < 256) {
            const int rsel = tid >> 7;                 // 0: row 0, 1: row 129
            const int q = tid & 127;
            const int slot = rsel ? 32 : 1;
            const int grr = reflect_idx(gr0 + (rsel ? 129 : 0));
            const int lo = (q & ~3) | ((q & 1) << 1) | ((q >> 1) & 1);   // swap low 2 bits
            buf[0][slot * PITCH + lo] = src[base + grr * NX + reflect_idx(gc0 + q)];
        }
    }

    const v2f qq = (v2f){0.25f, 0.25f};
    const int wT = (2 * c) * PITCH + C0;         // row R0   = bottom halo of chunk c-1
    const int wB = (2 * c + 3) * PITCH + C0;     // row R0+7 = top halo of chunk c+1
    const int rT = (2 * c + 1) * PITCH + C0;     // own top halo (row 8c)
    const int rB = (2 * c + 2) * PITCH + C0;     // own bottom halo (row 8c+9)

    // ---- staging epilogue: publish S0 boundary rows into buf[0] ----
    // LDS layout within a slot row is (E.x,E.y,O.x,O.y) at C0 -> two b64s.
    *(v2f*)&buf[0][wT]     = E[0];
    *(v2f*)&buf[0][wT + 2] = O[0];
    *(v2f*)&buf[0][wB]     = E[7];
    *(v2f*)&buf[0][wB + 2] = O[7];

    // ---- T fused steps; one barrier per step, reads early / writes mid ----
#pragma unroll
    for (int s = 0; s < T; ++s) {
        __syncthreads();
        const float* rb = buf[s & 1];
        float* wb = buf[(s + 1) & 1];
        const float4 t  = *(const float4*)&rb[rT];
        const float4 bo = *(const float4*)&rb[rB];

        // save old rows 0,1 (overwritten before row 0 is computed)
        const v2f oE0 = E[0], oO0 = O[0], oE1 = E[1], oO1 = O[1];
        v2f upE = E[0], upO = O[0];

        // rows 1..3 — register-only, cover the ds_read latency
#pragma unroll
        for (int i = 1; i <= 3; ++i) {
            v2f sE = E[i], sO = O[i];
            jrow(upE, upO, sE, sO, E[i + 1], O[i + 1], fE[i], fO[i], qq, E[i], O[i]);
            upE = sE; upO = sO;
        }

        // row 0 — first use of the top halo
        {
            v2f topE = (v2f){t.x, t.y}, topO = (v2f){t.z, t.w};
            jrow(topE, topO, oE0, oO0, oE1, oO1, fE[0], fO[0], qq, E[0], O[0]);
        }
        if (s + 1 < T) {                      // publish new row 0 mid-step
            *(v2f*)&wb[wT]     = E[0];
            *(v2f*)&wb[wT + 2] = O[0];
        }

        // rows 4..6 — register-only
#pragma unroll
        for (int i = 4; i <= 6; ++i) {
            v2f sE = E[i], sO = O[i];
            jrow(upE, upO, sE, sO, E[i + 1], O[i + 1], fE[i], fO[i], qq, E[i], O[i]);
            upE = sE; upO = sO;
        }

        // row 7 — first use of the bottom halo
        {
            v2f botE = (v2f){bo.x, bo.y}, botO = (v2f){bo.z, bo.w};
            jrow(upE, upO, E[7], O[7], botE, botO, fE[7], fO[7], qq, E[7], O[7]);
        }
        if (s + 1 < T) {                      // publish new row 7 late
            *(v2f*)&wb[wB]     = E[7];
            *(v2f*)&wb[wB + 2] = O[7];
        }
    }

    // ---- store kept window: rows T..129-T, tile cols 16..111 (aligned) ----
    const bool ok0 = (C0 >= T16) && (C0 < T16 + OUTC) && (gc0 + C0 + 1 < NX);
    const bool ok1 = (C0 + 2 >= T16) && (C0 + 2 < T16 + OUTC) && (gc0 + C0 + 3 < NX);
#pragma unroll
    for (int i = 0; i < 8; ++i) {
        const int br = R0 + i;
        const bool rowok = (br >= T) && (br <= 129 - T) && (gr0 + br < NX);
        if (rowok && ok0)
            *(v2f*)(dst + base + (gr0 + br) * NX + gc0 + C0) = (v2f){E[i].x, O[i].x};
        if (rowok && ok1)
            *(v2f*)(dst + base + (gr0 + br) * NX + gc0 + C0 + 2) = (v2f){E[i].y, O[i].y};
    }
}

extern "C" void kernel_launch(void* const* d_in, const int* in_sizes, int n_in,
                              void* d_out, int out_size, void* d_ws, size_t ws_size,
                              hipStream_t stream) {
    const float* layout = (const float*)d_in[0];
    const float* heat   = (const float*)d_in[1];
    float* out = (float*)d_out;
    float* ws  = (float*)d_ws;

    // T=13: OUTR = 130-2*13 = 104 -> grid rows ceil(1024/104) = 10
    // T=11: OUTR = 130-2*11 = 108 -> grid rows ceil(1024/108) = 10
    const dim3 g13(11, 10, BATCH), g11(11, 10, BATCH);
    const dim3 block(512);

    jacobi_fused<13, 104><<<g13, block, 0, stream>>>(heat, layout, ws);
    jacobi_fused<13, 104><<<g13, block, 0, stream>>>(ws,   layout, out);
    jacobi_fused<13, 104><<<g13, block, 0, stream>>>(out,  layout, ws);
    jacobi_fused<11, 108><<<g11, block, 0, stream>>>(ws,   layout, out);
}